// Round 12
// baseline (212.073 us; speedup 1.0000x reference)
//
#include <hip/hip_runtime.h>
#include <hip/hip_bf16.h>
#include <math.h>

#define BB 2
#define SS 2048
#define DIM 1024
#define NH 16
#define DH 64

typedef __bf16 bf16x8 __attribute__((ext_vector_type(8)));
typedef float f32x4 __attribute__((ext_vector_type(4)));
typedef float f32x16 __attribute__((ext_vector_type(16)));
typedef unsigned int u32x4 __attribute__((ext_vector_type(4)));

#define PENL2 (1000000.0f * 1.44269504f)

// counted vmem wait: prefetches stay in flight across barriers
#define VMW(N) asm volatile("s_waitcnt vmcnt(" #N ")" ::: "memory")
#define LGKM0() asm volatile("s_waitcnt lgkmcnt(0)" ::: "memory")

__device__ __forceinline__ void glds16(const __hip_bfloat16* g, __hip_bfloat16* l) {
    __builtin_amdgcn_global_load_lds(
        (const __attribute__((address_space(1))) void*)g,
        (__attribute__((address_space(3))) void*)l, 16, 0, 0);
}

__device__ __forceinline__ void glds4(const float* g, float* l) {
    __builtin_amdgcn_global_load_lds(
        (const __attribute__((address_space(1))) void*)g,
        (__attribute__((address_space(3))) void*)l, 4, 0, 0);
}

// fast fp32 -> bf16 (round-half-up, finite inputs)
__device__ __forceinline__ unsigned short f2bf(float x) {
    unsigned int u = __builtin_bit_cast(unsigned int, x);
    return (unsigned short)((u + 0x8000u) >> 16);
}

// pack two fp32 -> two bf16 in one register (hw op when available)
__device__ __forceinline__ unsigned int pk2bf(float a, float b) {
#if __has_builtin(__builtin_amdgcn_cvt_pk_bf16_f32)
    typedef __bf16 bf16x2 __attribute__((ext_vector_type(2)));
    bf16x2 p = __builtin_amdgcn_cvt_pk_bf16_f32(a, b);
    return __builtin_bit_cast(unsigned int, p);
#else
    return (unsigned int)f2bf(a) | ((unsigned int)f2bf(b) << 16);
#endif
}

__device__ __forceinline__ float fexp2(float x) {
#if __has_builtin(__builtin_amdgcn_exp2f)
    return __builtin_amdgcn_exp2f(x);
#else
    return exp2f(x);
#endif
}

__device__ __forceinline__ float frcp(float x) {
#if __has_builtin(__builtin_amdgcn_rcpf)
    return __builtin_amdgcn_rcpf(x);   // 1ulp fp32 rcp; ample for bf16 output
#else
    return 1.0f / x;
#endif
}

// ------- prep (fused): z<4 -> transpose W[z] [K,N]->[N,K] bf16; z==4 -> cast X
//         (+ first 16 blocks also precompute pf = -PENL2*(1-mask)) -------
__global__ void prep(const float* __restrict__ X,
                     const float* __restrict__ Wq, const float* __restrict__ Wk,
                     const float* __restrict__ Wv, const float* __restrict__ Wo,
                     const float* __restrict__ mask, float* __restrict__ pf,
                     __hip_bfloat16* __restrict__ T4, ushort4* __restrict__ Xbf) {
    int z = blockIdx.z;
    int t = threadIdx.x;
    if (z == 4) {
        // cast X: 1024 blocks (bx + by*32), 4096 floats each
        int c = blockIdx.y * 32 + blockIdx.x;
        const float4* in = (const float4*)X;
#pragma unroll
        for (int k = 0; k < 4; ++k) {
            int i = c * 1024 + k * 256 + t;
            float4 v = in[i];
            ushort4 h;
            h.x = f2bf(v.x); h.y = f2bf(v.y); h.z = f2bf(v.z); h.w = f2bf(v.w);
            Xbf[i] = h;
        }
        if (c < 16) {
            int i = c * 256 + t;   // covers B*S = 4096
            pf[i] = -PENL2 * (1.0f - mask[i]);
        }
        return;
    }
    const float* W = (z == 0) ? Wq : (z == 1) ? Wk : (z == 2) ? Wv : Wo;
    __hip_bfloat16* Thi = T4 + (size_t)z * DIM * DIM;
    __shared__ float tile[32][33];
    int k0 = blockIdx.x * 32, n0 = blockIdx.y * 32;
    int r = t >> 3, c = (t & 7) << 2;
    float4 v = *(const float4*)&W[(size_t)(k0 + r) * DIM + n0 + c];
    tile[r][c] = v.x; tile[r][c + 1] = v.y; tile[r][c + 2] = v.z; tile[r][c + 3] = v.w;
    __syncthreads();
    size_t base = (size_t)(n0 + r) * DIM + k0 + c;
#pragma unroll
    for (int i = 0; i < 4; ++i)
        ((unsigned short*)Thi)[base + i] = f2bf(tile[c + i][r]);
}

// ------- bf16 MFMA GEMM (QKV), 128x128 tile, 8 waves, depth-2 prefetch
//         (3 LDS bufs), counted vmcnt + raw barriers, chunk-XOR-swizzled LDS.
//         Verified structure (rounds 4-11). mode 1 only in current launcher. -------
#define BM 128
#define BK 32
#define QSCALE (0.125f * 1.44269504f)   // fold softmax scale + log2e into Q
template <int TBN>
__global__ __launch_bounds__(512, 6) void gemm_bf(
    const __hip_bfloat16* __restrict__ A, const __hip_bfloat16* __restrict__ B,
    const float* __restrict__ b0, const float* __restrict__ b1, const float* __restrict__ b2,
    __hip_bfloat16* __restrict__ oq, __hip_bfloat16* __restrict__ ok,
    __hip_bfloat16* __restrict__ ov, float* __restrict__ of32, int mode) {
    __shared__ alignas(16) __hip_bfloat16 sA[3][BM * BK];
    __shared__ alignas(16) __hip_bfloat16 sB[3][TBN * BK];
    const int K = 1024;
    const int JF = TBN / 64;           // j-fragments per wave (2 or 1)
    int tid = threadIdx.x;
    int wave = tid >> 6, lane = tid & 63, quad = lane >> 4, l16 = lane & 15;

    // XCD-aware bijective swizzle: grid sizes %8==0.
    int nbx = gridDim.x;
    int nwg = nbx * gridDim.y;
    int bid = blockIdx.y * nbx + blockIdx.x;
    int swz = (bid & 7) * (nwg >> 3) + (bid >> 3);
    int m0 = (swz / nbx) * BM, n0 = (swz % nbx) * TBN;
    // 8 waves: 2 (m) x 4 (n); each wave owns a 64x(TBN/4) output sub-tile
    int mo = (wave >> 2) * 64, no = (wave & 3) * (TBN / 4);

    f32x4 acc[4][JF];
#pragma unroll
    for (int i = 0; i < 4; ++i)
#pragma unroll
        for (int j = 0; j < JF; ++j) acc[i][j] = (f32x4){0.f, 0.f, 0.f, 0.f};

    int ar = tid >> 2;                 // 0..127
    int c4 = tid & 3;                  // physical chunk slot
    int cs = c4 ^ ((ar >> 1) & 3);     // logical (source) chunk
    const __hip_bfloat16* gA = A + (size_t)(m0 + ar) * K + cs * 8;
    const __hip_bfloat16* gB = B + (size_t)(n0 + ar) * K + cs * 8;
    int ldst = ar * BK + c4 * 8;       // linear dest element offset
    bool stgB = (ar < TBN);            // wave-uniform (ar spans 16 per wave)

    auto STG = [&](int bb, int k0) {
        glds16(gA + k0, &sA[bb][ldst]);
        if (stgB) glds16(gB + k0, &sB[bb][ldst]);
    };

    STG(0, 0);
    STG(1, BK);
    int cur = 0;
    for (int it = 0; it < 32; ++it) {
        int k0 = it * BK;
        if (it < 30) {
            int nb = cur + 2; if (nb >= 3) nb -= 3;
            STG(nb, k0 + 2 * BK);
            // wait for buf cur's loads: 2/STG for A+B waves, 1/STG for A-only
            if (stgB) { VMW(4); } else { VMW(2); }
        } else if (it == 30) {
            if (stgB) { VMW(2); } else { VMW(1); }
        } else {
            VMW(0);
        }
        __builtin_amdgcn_s_barrier();   // all waves: buf[cur] staged

        bf16x8 a_h[4], b_h[JF];
#pragma unroll
        for (int i = 0; i < 4; ++i) {
            int rr = mo + i * 16 + l16;
            int ph = quad ^ ((rr >> 1) & 3);
            a_h[i] = *(const bf16x8*)&sA[cur][rr * BK + ph * 8];
        }
#pragma unroll
        for (int j = 0; j < JF; ++j) {
            int rr = no + j * 16 + l16;
            int ph = quad ^ ((rr >> 1) & 3);
            b_h[j] = *(const bf16x8*)&sB[cur][rr * BK + ph * 8];
        }
        __builtin_amdgcn_s_setprio(1);
#pragma unroll
        for (int i = 0; i < 4; ++i)
#pragma unroll
            for (int j = 0; j < JF; ++j)
                acc[i][j] = __builtin_amdgcn_mfma_f32_16x16x32_bf16(a_h[i], b_h[j], acc[i][j], 0, 0, 0);
        __builtin_amdgcn_s_setprio(0);
        __builtin_amdgcn_s_barrier();   // reads of buf[cur] done before overwrite
        cur = (cur == 2) ? 0 : cur + 1;
    }

    int which = (mode == 1) ? (n0 >> 10) : 0;
    const float* bp = (mode == 0) ? b0 : (which == 0) ? b0 : (which == 1) ? b1 : b2;
#pragma unroll
    for (int i = 0; i < 4; ++i)
#pragma unroll
        for (int j = 0; j < JF; ++j) {
            int gmb = m0 + mo + i * 16 + quad * 4;
            int gn  = n0 + no + j * 16 + l16;
            int nn  = gn & 1023;
            float bb = bp[(mode == 0) ? gn : nn];
#pragma unroll
            for (int r = 0; r < 4; ++r) {
                int gm = gmb + r;
                float v = acc[i][j][r] + bb;
                if (mode == 0) {
                    of32[(size_t)gm * 1024 + gn] = v;
                } else {
                    int b = gm >> 11, s = gm & 2047, h = nn >> 6, d = nn & 63;
                    if (which == 0)
                        ((unsigned short*)oq)[(((size_t)(b * NH + h)) * SS + s) * DH + d] = f2bf(v * QSCALE);
                    else if (which == 1)
                        ((unsigned short*)ok)[(((size_t)(b * NH + h)) * SS + s) * DH + d] = f2bf(v);
                    else
                        ((unsigned short*)ov)[(((size_t)(b * NH + h)) * DH + d) * SS + s] = f2bf(v);
                }
            }
        }
}

// ------- O-projection GEMM with FUSED combine, v2: depth-2 pipeline.
//         A = (O1+O2)/(l1+l2) computed in regs; loads for tile it+2 issue at
//         iter it (2-iteration latency window, as verified in gemm_bf);
//         transform of tile it+1 lands in sA[(it+1)%3] before barrier.
//         Counted vmcnt per wave class: allowed-in-flight after transform is
//         {B(it+1), A/l/B(it+2)} = 6 for B-staging waves, 4 for A-only waves;
//         B(it) is strictly older than all of them -> drained. lgkmcnt(0)
//         before barrier makes the ds_writes visible. 2 barriers/iter (same
//         buffer-overwrite separation argument as gemm_bf). -------
__global__ __launch_bounds__(512, 4) void gemm_of(
    const __hip_bfloat16* __restrict__ O1, const __hip_bfloat16* __restrict__ O2,
    const float* __restrict__ l1, const float* __restrict__ l2,
    const __hip_bfloat16* __restrict__ Bw,    // Wot [N=1024][K=1024]
    const float* __restrict__ bias, float* __restrict__ out) {
    __shared__ alignas(16) __hip_bfloat16 sA[3][BM * BK];
    __shared__ alignas(16) __hip_bfloat16 sB[3][64 * BK];
    int tid = threadIdx.x;
    int wave = tid >> 6, lane = tid & 63, quad = lane >> 4, l16 = lane & 15;

    int nbx = gridDim.x;               // 16
    int nwg = nbx * gridDim.y;         // 512, %8==0
    int bid = blockIdx.y * nbx + blockIdx.x;
    int swz = (bid & 7) * (nwg >> 3) + (bid >> 3);
    int m0 = (swz / nbx) * BM, n0 = (swz % nbx) * 64;
    int mo = (wave >> 2) * 64, no = (wave & 3) * 16;

    f32x4 acc[4];
#pragma unroll
    for (int i = 0; i < 4; ++i) acc[i] = (f32x4){0.f, 0.f, 0.f, 0.f};

    int ar = tid >> 2;                 // 0..127
    int c4 = tid & 3;
    int cs = c4 ^ ((ar >> 1) & 3);     // logical chunk (XOR swizzle, as gemm_bf)
    int m  = m0 + ar;
    int bq16 = (m >> 11) * NH;         // b*16
    int sq   = m & 2047;
    const __hip_bfloat16* gO1 = O1 + (size_t)m * 1024 + cs * 8;
    const __hip_bfloat16* gO2 = O2 + (size_t)m * 1024 + cs * 8;
    const __hip_bfloat16* gB  = Bw + (size_t)(n0 + ar) * 1024 + cs * 8;
    int ldst = ar * BK + c4 * 8;
    bool stgB = (ar < 64);             // wave-uniform

    // transform helper is a macro over NAMED regs (no dynamic-indexed arrays)
#define OF_XFORM(N1, N2, NL, BUF)                                              \
    {                                                                          \
        float linv = frcp(NL);                                                 \
        unsigned int p0 = pk2bf(((float)N1[0]+(float)N2[0])*linv,              \
                                ((float)N1[1]+(float)N2[1])*linv);             \
        unsigned int p1 = pk2bf(((float)N1[2]+(float)N2[2])*linv,              \
                                ((float)N1[3]+(float)N2[3])*linv);             \
        unsigned int p2 = pk2bf(((float)N1[4]+(float)N2[4])*linv,              \
                                ((float)N1[5]+(float)N2[5])*linv);             \
        unsigned int p3 = pk2bf(((float)N1[6]+(float)N2[6])*linv,              \
                                ((float)N1[7]+(float)N2[7])*linv);             \
        u32x4 pw_; pw_.x = p0; pw_.y = p1; pw_.z = p2; pw_.w = p3;             \
        *(bf16x8*)&sA[BUF][ldst] = __builtin_bit_cast(bf16x8, pw_);            \
    }

#define OF_LOAD(N1, N2, NL, KOFF)                                              \
    {                                                                          \
        N1 = *(const bf16x8*)(gO1 + (KOFF));                                   \
        N2 = *(const bf16x8*)(gO2 + (KOFF));                                   \
        size_t bhq_ = (size_t)(bq16 + ((KOFF) >> 6)) * SS + sq;                \
        NL = l1[bhq_] + l2[bhq_];                                              \
        if (stgB) glds16(gB + (KOFF), &sB[(KOFF / BK) % 3][ldst]);             \
    }

    // one pipeline step: transform set P (data for tile it+1) into sA[(it+1)%3];
    // load set L with data for tile it+2; compute tile it from buf[cur].
#define OF_STEP(IT, P1, P2, PL, L1_, L2_, LL)                                  \
    {                                                                          \
        int it = (IT);                                                         \
        if (it < 30) { OF_LOAD(L1_, L2_, LL, (it + 2) * BK); }                 \
        if (it < 31) {                                                         \
            int nxt = cur + 1; if (nxt >= 3) nxt -= 3;                         \
            OF_XFORM(P1, P2, PL, nxt);                                         \
        }                                                                      \
        if (it < 30)      { if (stgB) { VMW(6); } else { VMW(4); } }           \
        else if (it == 30){ if (stgB) { VMW(1); } else { VMW(0); } }           \
        else              { VMW(0); }                                          \
        LGKM0();                                                               \
        __builtin_amdgcn_s_barrier();                                          \
        bf16x8 a_h[4], b_h;                                                    \
        _Pragma("unroll")                                                      \
        for (int i = 0; i < 4; ++i) {                                          \
            int rr = mo + i * 16 + l16;                                        \
            int ph = quad ^ ((rr >> 1) & 3);                                   \
            a_h[i] = *(const bf16x8*)&sA[cur][rr * BK + ph * 8];               \
        }                                                                      \
        {                                                                      \
            int rr = no + l16;                                                 \
            int ph = quad ^ ((rr >> 1) & 3);                                   \
            b_h = *(const bf16x8*)&sB[cur][rr * BK + ph * 8];                  \
        }                                                                      \
        __builtin_amdgcn_s_setprio(1);                                         \
        _Pragma("unroll")                                                      \
        for (int i = 0; i < 4; ++i)                                            \
            acc[i] = __builtin_amdgcn_mfma_f32_16x16x32_bf16(a_h[i], b_h, acc[i], 0, 0, 0); \
        __builtin_amdgcn_s_setprio(0);                                         \
        __builtin_amdgcn_s_barrier();                                          \
        cur = (cur == 2) ? 0 : cur + 1;                                        \
    }

    // ---- prologue: tiles 0 and 1 ----
    bf16x8 na1, na2, nb1, nb2;
    float  nla, nlb;
    OF_LOAD(na1, na2, nla, 0);      // A(0)+B(0) -> sB[0]
    OF_LOAD(nb1, nb2, nlb, BK);     // A(1)+B(1) -> sB[1]
    OF_XFORM(na1, na2, nla, 0);     // sA[0]  (auto-waits A(0)/l(0) regs)
    __syncthreads();                // full drain once: sA[0], sB[0], sB[1] ready

    int cur = 0;
    // at iter it: transform set holding A(it+1), load A(it+2) into other set.
    // A(1) sits in the b-set; iter 0 loads A(2) into the a-set; alternate.
    for (int it2 = 0; it2 < 32; it2 += 2) {
        OF_STEP(it2,     nb1, nb2, nlb, na1, na2, nla);
        OF_STEP(it2 + 1, na1, na2, nla, nb1, nb2, nlb);
    }

    // epilogue: C[m][n] + bias
#pragma unroll
    for (int i = 0; i < 4; ++i) {
        int gmb = m0 + mo + i * 16 + quad * 4;
        int gn  = n0 + no + l16;
        float bb = bias[gn];
#pragma unroll
        for (int r = 0; r < 4; ++r)
            out[(size_t)(gmb + r) * 1024 + gn] = acc[i][r] + bb;
    }
#undef OF_STEP
#undef OF_LOAD
#undef OF_XFORM
}

// ----- flash v13 (verified 52.6-53.4us): swapped QK^T (32x32x16), penalty
//       staged through LDS as MFMA C-in, in-register softmax via cvt_pk +
//       v_permlane32_swap, XCD-aware work remap, single-barrier double-
//       buffered glds staging, setprio around MFMA clusters. -----
__global__ __launch_bounds__(256, 4) void flash_split(
        const __hip_bfloat16* __restrict__ Q,
        const __hip_bfloat16* __restrict__ K,
        const __hip_bfloat16* __restrict__ Vt,
        const float* __restrict__ pf,     // -PENL2*(1-mask), [B,S]
        __hip_bfloat16* __restrict__ Op0, __hip_bfloat16* __restrict__ Op1,
        float* __restrict__ lp0, float* __restrict__ lp1) {
    // hw linear id (x fastest), bijective XCD remap: w = (bid%8)*128 + bid/8
    int bidl = blockIdx.x + (blockIdx.y << 4) + (blockIdx.z << 9);   // grid (16,32,2)
    int w = (bidl & 7) * 128 + (bidl >> 3);
    int q0 = (w & 15) * 128;
    int bh = (w >> 4) & 31;
    int z  = w >> 9;
    int b = bh >> 4, h = bh & (NH - 1);
    __hip_bfloat16* Op = z ? Op1 : Op0;
    float*          lp = z ? lp1 : lp0;
    int tid = threadIdx.x;
    int wave = tid >> 6, lane = tid & 63;
    int l31 = lane & 31, hi = lane >> 5, l7 = lane & 7;

    // [64 rows][64 elems] bf16 = 8 KB each, double-buffered: 32 KB total
    __shared__ alignas(16) __hip_bfloat16 sK[2][64 * 64];
    __shared__ alignas(16) __hip_bfloat16 sV[2][64 * 64];
    __shared__ alignas(16) float sPF[2][64];   // staged penalty per 64-key tile

    // Q fragment (B operand): row q = l31 (+wave*32), k(d) = dstep*16 + 8*hi + j
    const __hip_bfloat16* Qrow = Q + ((size_t)bh * SS + q0 + wave * 32 + l31) * DH;
    bf16x8 aq[4];
#pragma unroll
    for (int d_ = 0; d_ < 4; ++d_)
        aq[d_] = *(const bf16x8*)(Qrow + d_ * 16 + 8 * hi);

    const __hip_bfloat16* Kb = K + (size_t)bh * SS * DH;
    const __hip_bfloat16* Vb = Vt + (size_t)bh * DH * SS;
    const float* pfp = pf + b * SS;

    f32x16 z16;
#pragma unroll
    for (int r = 0; r < 16; ++r) z16[r] = 0.f;
    f32x16 O[2];
    O[0] = z16; O[1] = z16;
    f32x4 ls = (f32x4){0.f, 0.f, 0.f, 0.f};

    // swizzled read offsets (bytes): chunk c2 = (c<<1)|hi, xor'd with row&7 (= l7)
    int xo[4];
#pragma unroll
    for (int c = 0; c < 4; ++c) xo[c] = ((((c << 1) | hi) ^ l7) << 4);

    // staging geometry: per wave, lane l covers row (l>>3), chunk (l&7) -> dest byte = lane*16
    int r8 = lane >> 3, c8 = lane & 7;
    int ck = c8 ^ r8;   // inverse-swizzled SOURCE chunk (row&7 == r8)

    const int kbeg = z * (SS / 2);
    const int NT = (SS / 2) / 64;

    auto STAGE = [&](int bb, int k0) {
#pragma unroll
        for (int cc = 0; cc < 2; ++cc) {
            int row = cc * 32 + wave * 8 + r8;
            glds16(Kb + (size_t)(k0 + row) * DH + ck * 8, &sK[bb][row * 64 + c8 * 8]);
            glds16(Vb + (size_t)row * SS + k0 + ck * 8,  &sV[bb][row * 64 + c8 * 8]);
        }
        if (wave == 0)                      // 64 lanes x 4B = full 256B pf slice
            glds4(pfp + k0 + lane, &sPF[bb][0]);
    };

    STAGE(0, kbeg);
    __syncthreads();
    int cur = 0;
    for (int t = 0; t < NT; ++t) {
        int k0 = kbeg + t * 64;
        if (t + 1 < NT) STAGE(cur ^ 1, k0 + 64);
#pragma unroll
        for (int tt = 0; tt < 2; ++tt) {   // two 32-key tiles
            // --- QK^T swapped: C[k][q], k = (r&3)+8*(r>>2)+4*hi, q = l31 ---
            const char* pK = (const char*)&sK[cur][(tt * 32 + l31) * 64];
            bf16x8 kf[4];
#pragma unroll
            for (int d_ = 0; d_ < 4; ++d_)
                kf[d_] = *(const bf16x8*)(pK + xo[d_]);
            // C-in = log2-domain penalty from LDS (broadcast reads, staged ahead)
            f32x16 st;
#pragma unroll
            for (int g = 0; g < 4; ++g) {
                f32x4 pv = *(const f32x4*)&sPF[cur][32 * tt + 8 * g + 4 * hi];
#pragma unroll
                for (int j = 0; j < 4; ++j) st[4 * g + j] = pv[j];
            }
            __builtin_amdgcn_s_setprio(1);
#pragma unroll
            for (int d_ = 0; d_ < 4; ++d_)
                st = __builtin_amdgcn_mfma_f32_32x32x16_bf16(kf[d_], aq[d_], st, 0, 0, 0);
            __builtin_amdgcn_s_setprio(0);

            // --- softmax numerator in-register: e = exp2(s + pen) ---
#pragma unroll
            for (int g = 0; g < 4; ++g) {
#pragma unroll
                for (int j = 0; j < 4; ++j)
                    st[4 * g + j] = fexp2(st[4 * g + j]);
                ls[0] += st[4 * g];     ls[1] += st[4 * g + 1];
                ls[2] += st[4 * g + 2]; ls[3] += st[4 * g + 3];
            }

            // --- pack pairs to bf16: u[2g+p] holds keys 8g+4hi+2p+{0,1} ---
            unsigned int u[8];
#pragma unroll
            for (int g = 0; g < 4; ++g) {
                u[2 * g]     = pk2bf(st[4 * g],     st[4 * g + 1]);
                u[2 * g + 1] = pk2bf(st[4 * g + 2], st[4 * g + 3]);
            }

            // --- build PV A-frags (k = 16*ks + 8*hi + j) via permlane32_swap ---
#pragma unroll
            for (int kk = 0; kk < 2; ++kk) {   // ks = 2*tt + kk
                unsigned int w0 = u[4 * kk],     w2 = u[4 * kk + 2];
                unsigned int w1 = u[4 * kk + 1], w3 = u[4 * kk + 3];
                asm("v_permlane32_swap_b32 %0, %1" : "+v"(w0), "+v"(w2));
                asm("v_permlane32_swap_b32 %0, %1" : "+v"(w1), "+v"(w3));
                u32x4 paw; paw.x = w0; paw.y = w1; paw.z = w2; paw.w = w3;
                bf16x8 pa = __builtin_bit_cast(bf16x8, paw);
                int ks = 2 * tt + kk;
                __builtin_amdgcn_s_setprio(1);
#pragma unroll
                for (int dt_ = 0; dt_ < 2; ++dt_) {
                    const char* pV = (const char*)&sV[cur][(dt_ * 32 + l31) * 64];
                    bf16x8 vf = *(const bf16x8*)(pV + xo[ks]);
                    O[dt_] = __builtin_amdgcn_mfma_f32_32x32x16_bf16(pa, vf, O[dt_], 0, 0, 0);
                }
                __builtin_amdgcn_s_setprio(0);
            }
        }
        __syncthreads();
        cur ^= 1;
    }

    // --- epilogue: O is C[q][d], q = (r&3)+8*(r>>2)+4*hi, d = dt*32 + l31 ---
    unsigned short* op = (unsigned short*)Op;
    int qb = q0 + wave * 32;
#pragma unroll
    for (int dt_ = 0; dt_ < 2; ++dt_)
#pragma unroll
        for (int r = 0; r < 16; ++r) {
            int qq = (r & 3) + 8 * (r >> 2) + 4 * hi;
            op[((size_t)b * SS + qb + qq) * (NH * DH) + h * DH + dt_ * 32 + l31] =
                f2bf(O[dt_][r]);
        }
    float lt = ls[0] + ls[1] + ls[2] + ls[3];
    lt += __shfl_xor(lt, 32, 64);
    if (hi == 0)
        lp[(size_t)bh * SS + qb + l31] = lt;
}

extern "C" void kernel_launch(void* const* d_in, const int* in_sizes, int n_in,
                              void* d_out, int out_size, void* d_ws, size_t ws_size,
                              hipStream_t stream) {
    const float* X    = (const float*)d_in[0];
    const float* mask = (const float*)d_in[1];
    const float* Wq   = (const float*)d_in[2];
    const float* bq   = (const float*)d_in[3];
    const float* Wk   = (const float*)d_in[4];
    const float* bk   = (const float*)d_in[5];
    const float* Wv   = (const float*)d_in[6];
    const float* bv   = (const float*)d_in[7];
    const float* Wo   = (const float*)d_in[8];
    const float* bo   = (const float*)d_in[9];
    float* out = (float*)d_out;

    const size_t MB = 1u << 20;
    char* ws = (char*)d_ws;
    __hip_bfloat16* Xbf = (__hip_bfloat16*)(ws);             // 0-8
    __hip_bfloat16* Op0 = (__hip_bfloat16*)(ws + 8 * MB);    // 8-16
    __hip_bfloat16* Wt4 = (__hip_bfloat16*)(ws + 16 * MB);   // 16-24 (Wq,Wk,Wv,Wo ^T)
    float*          lp0 = (float*)(ws + 24 * MB);            // 24-24.25
    float*          lp1 = (float*)(ws + 25 * MB);            // 25-25.25
    float*          pf  = (float*)(ws + 26 * MB);            // 26-26.02 (penalty)
    __hip_bfloat16* Qw  = (__hip_bfloat16*)(ws + 32 * MB);   // 32-40
    __hip_bfloat16* Kw  = (__hip_bfloat16*)(ws + 40 * MB);   // 40-48
    __hip_bfloat16* Vt  = (__hip_bfloat16*)(ws + 48 * MB);   // 48-56
    __hip_bfloat16* Op1 = (__hip_bfloat16*)(ws + 56 * MB);   // 56-64
    __hip_bfloat16* Wot = Wt4 + (size_t)3 * DIM * DIM;       // 22-24

    dim3 pgrd(32, 32, 5);
    prep<<<pgrd, 256, 0, stream>>>(X, Wq, Wk, Wv, Wo, mask, pf, Wt4, (ushort4*)Xbf);

    dim3 qkvgrd(3 * DIM / 128, (BB * SS) / BM);  // (24, 32) = 768 blocks, %8==0
    gemm_bf<128><<<qkvgrd, 512, 0, stream>>>(Xbf, Wt4, bq, bk, bv,
                                             Qw, Kw, Vt, nullptr, 1);

    dim3 agrd(SS / 128, BB * NH, 2);             // (16, 32, 2) = 1024 blocks
    flash_split<<<agrd, 256, 0, stream>>>(Qw, Kw, Vt, pf, Op0, Op1, lp0, lp1);

    // O-projection with fused combine (depth-2 pipelined)
    dim3 ogrd(DIM / 64, (BB * SS) / BM);         // (16, 32) = 512 blocks, %8==0
    gemm_of<<<ogrd, 512, 0, stream>>>(Op0, Op1, lp0, lp1, Wot, bo, out);
}

// Round 13
// 205.139 us; speedup vs baseline: 1.0338x; 1.0338x over previous
//
#include <hip/hip_runtime.h>
#include <hip/hip_bf16.h>
#include <math.h>

#define BB 2
#define SS 2048
#define DIM 1024
#define NH 16
#define DH 64

typedef __bf16 bf16x8 __attribute__((ext_vector_type(8)));
typedef float f32x4 __attribute__((ext_vector_type(4)));
typedef float f32x16 __attribute__((ext_vector_type(16)));
typedef unsigned int u32x4 __attribute__((ext_vector_type(4)));

#define PENL2 (1000000.0f * 1.44269504f)

// counted vmem wait: prefetches stay in flight across barriers
#define VMW(N) asm volatile("s_waitcnt vmcnt(" #N ")" ::: "memory")

__device__ __forceinline__ void glds16(const __hip_bfloat16* g, __hip_bfloat16* l) {
    __builtin_amdgcn_global_load_lds(
        (const __attribute__((address_space(1))) void*)g,
        (__attribute__((address_space(3))) void*)l, 16, 0, 0);
}

__device__ __forceinline__ void glds4(const float* g, float* l) {
    __builtin_amdgcn_global_load_lds(
        (const __attribute__((address_space(1))) void*)g,
        (__attribute__((address_space(3))) void*)l, 4, 0, 0);
}

// fast fp32 -> bf16 (round-half-up, finite inputs)
__device__ __forceinline__ unsigned short f2bf(float x) {
    unsigned int u = __builtin_bit_cast(unsigned int, x);
    return (unsigned short)((u + 0x8000u) >> 16);
}

// pack two fp32 -> two bf16 in one register (hw op when available)
__device__ __forceinline__ unsigned int pk2bf(float a, float b) {
#if __has_builtin(__builtin_amdgcn_cvt_pk_bf16_f32)
    typedef __bf16 bf16x2 __attribute__((ext_vector_type(2)));
    bf16x2 p = __builtin_amdgcn_cvt_pk_bf16_f32(a, b);
    return __builtin_bit_cast(unsigned int, p);
#else
    return (unsigned int)f2bf(a) | ((unsigned int)f2bf(b) << 16);
#endif
}

__device__ __forceinline__ float fexp2(float x) {
#if __has_builtin(__builtin_amdgcn_exp2f)
    return __builtin_amdgcn_exp2f(x);
#else
    return exp2f(x);
#endif
}

// ------- prep (fused): z<4 -> transpose W[z] [K,N]->[N,K] bf16; z==4 -> cast X
//         (+ first 16 blocks also precompute pf = -PENL2*(1-mask)) -------
__global__ void prep(const float* __restrict__ X,
                     const float* __restrict__ Wq, const float* __restrict__ Wk,
                     const float* __restrict__ Wv, const float* __restrict__ Wo,
                     const float* __restrict__ mask, float* __restrict__ pf,
                     __hip_bfloat16* __restrict__ T4, ushort4* __restrict__ Xbf) {
    int z = blockIdx.z;
    int t = threadIdx.x;
    if (z == 4) {
        // cast X: 1024 blocks (bx + by*32), 4096 floats each
        int c = blockIdx.y * 32 + blockIdx.x;
        const float4* in = (const float4*)X;
#pragma unroll
        for (int k = 0; k < 4; ++k) {
            int i = c * 1024 + k * 256 + t;
            float4 v = in[i];
            ushort4 h;
            h.x = f2bf(v.x); h.y = f2bf(v.y); h.z = f2bf(v.z); h.w = f2bf(v.w);
            Xbf[i] = h;
        }
        if (c < 16) {
            int i = c * 256 + t;   // covers B*S = 4096
            pf[i] = -PENL2 * (1.0f - mask[i]);
        }
        return;
    }
    const float* W = (z == 0) ? Wq : (z == 1) ? Wk : (z == 2) ? Wv : Wo;
    __hip_bfloat16* Thi = T4 + (size_t)z * DIM * DIM;
    __shared__ float tile[32][33];
    int k0 = blockIdx.x * 32, n0 = blockIdx.y * 32;
    int r = t >> 3, c = (t & 7) << 2;
    float4 v = *(const float4*)&W[(size_t)(k0 + r) * DIM + n0 + c];
    tile[r][c] = v.x; tile[r][c + 1] = v.y; tile[r][c + 2] = v.z; tile[r][c + 3] = v.w;
    __syncthreads();
    size_t base = (size_t)(n0 + r) * DIM + k0 + c;
#pragma unroll
    for (int i = 0; i < 4; ++i)
        ((unsigned short*)Thi)[base + i] = f2bf(tile[c + i][r]);
}

// ------- bf16 MFMA GEMM, 128xTBN tile, 8 waves, depth-2 prefetch (3 LDS bufs),
//         counted vmcnt + raw barriers, chunk-XOR-swizzled LDS -------
// vmcnt discipline: waves that stage A+B have 2 loads/STG; A-only waves have 1.
// The counted wait MUST match the per-wave issue rate (stgB ? 4 : 2), else
// A-only waves skip the wait and read unstaged LDS (round-9 absmax failure).
// mode 0: of32[m*1024+n] = acc + b0[n]   (TBN=64 for 2 blocks/CU occupancy)
// mode 1: fused QKV, N=3072 (TBN=128): n<1024 -> Q split-heads (PRE-SCALED),
//         <2048 -> K split-heads, else V^T [B,H,DH,S]
#define BM 128
#define BK 32
#define QSCALE (0.125f * 1.44269504f)   // fold softmax scale + log2e into Q
template <int TBN>
__global__ __launch_bounds__(512, 6) void gemm_bf(
    const __hip_bfloat16* __restrict__ A, const __hip_bfloat16* __restrict__ B,
    const float* __restrict__ b0, const float* __restrict__ b1, const float* __restrict__ b2,
    __hip_bfloat16* __restrict__ oq, __hip_bfloat16* __restrict__ ok,
    __hip_bfloat16* __restrict__ ov, float* __restrict__ of32, int mode) {
    __shared__ alignas(16) __hip_bfloat16 sA[3][BM * BK];
    __shared__ alignas(16) __hip_bfloat16 sB[3][TBN * BK];
    const int K = 1024;
    const int JF = TBN / 64;           // j-fragments per wave (2 or 1)
    int tid = threadIdx.x;
    int wave = tid >> 6, lane = tid & 63, quad = lane >> 4, l16 = lane & 15;

    // XCD-aware bijective swizzle: grid sizes (768, 512) are %8==0.
    int nbx = gridDim.x;
    int nwg = nbx * gridDim.y;
    int bid = blockIdx.y * nbx + blockIdx.x;
    int swz = (bid & 7) * (nwg >> 3) + (bid >> 3);
    int m0 = (swz / nbx) * BM, n0 = (swz % nbx) * TBN;
    // 8 waves: 2 (m) x 4 (n); each wave owns a 64x(TBN/4) output sub-tile
    int mo = (wave >> 2) * 64, no = (wave & 3) * (TBN / 4);

    f32x4 acc[4][JF];
#pragma unroll
    for (int i = 0; i < 4; ++i)
#pragma unroll
        for (int j = 0; j < JF; ++j) acc[i][j] = (f32x4){0.f, 0.f, 0.f, 0.f};

    // staging: 512 threads cover 128 rows x 4 chunks(16B) for A (TBN rows for B).
    // LDS dest is linear (tid*16B within wave); SOURCE chunk is inverse-swizzled
    // so that physical chunk c of row r holds logical chunk c ^ ((r>>1)&3).
    int ar = tid >> 2;                 // 0..127
    int c4 = tid & 3;                  // physical chunk slot
    int cs = c4 ^ ((ar >> 1) & 3);     // logical (source) chunk
    const __hip_bfloat16* gA = A + (size_t)(m0 + ar) * K + cs * 8;
    const __hip_bfloat16* gB = B + (size_t)(n0 + ar) * K + cs * 8;
    int ldst = ar * BK + c4 * 8;       // linear dest element offset
    bool stgB = (ar < TBN);            // wave-uniform (ar spans 16 per wave)

    auto STG = [&](int bb, int k0) {
        glds16(gA + k0, &sA[bb][ldst]);
        if (stgB) glds16(gB + k0, &sB[bb][ldst]);
    };

    STG(0, 0);
    STG(1, BK);
    int cur = 0;
    for (int it = 0; it < 32; ++it) {
        int k0 = it * BK;
        if (it < 30) {
            int nb = cur + 2; if (nb >= 3) nb -= 3;
            STG(nb, k0 + 2 * BK);
            // wait for buf cur's loads: 2/STG for A+B waves, 1/STG for A-only
            if (stgB) { VMW(4); } else { VMW(2); }
        } else if (it == 30) {
            if (stgB) { VMW(2); } else { VMW(1); }
        } else {
            VMW(0);
        }
        __builtin_amdgcn_s_barrier();   // all waves: buf[cur] staged

        bf16x8 a_h[4], b_h[JF];
#pragma unroll
        for (int i = 0; i < 4; ++i) {
            int rr = mo + i * 16 + l16;
            int ph = quad ^ ((rr >> 1) & 3);
            a_h[i] = *(const bf16x8*)&sA[cur][rr * BK + ph * 8];
        }
#pragma unroll
        for (int j = 0; j < JF; ++j) {
            int rr = no + j * 16 + l16;
            int ph = quad ^ ((rr >> 1) & 3);
            b_h[j] = *(const bf16x8*)&sB[cur][rr * BK + ph * 8];
        }
        __builtin_amdgcn_s_setprio(1);
#pragma unroll
        for (int i = 0; i < 4; ++i)
#pragma unroll
            for (int j = 0; j < JF; ++j)
                acc[i][j] = __builtin_amdgcn_mfma_f32_16x16x32_bf16(a_h[i], b_h[j], acc[i][j], 0, 0, 0);
        __builtin_amdgcn_s_setprio(0);
        __builtin_amdgcn_s_barrier();   // reads of buf[cur] done before overwrite
        cur = (cur == 2) ? 0 : cur + 1;
    }

    int which = (mode == 1) ? (n0 >> 10) : 0;
    const float* bp = (mode == 0) ? b0 : (which == 0) ? b0 : (which == 1) ? b1 : b2;
#pragma unroll
    for (int i = 0; i < 4; ++i)
#pragma unroll
        for (int j = 0; j < JF; ++j) {
            int gmb = m0 + mo + i * 16 + quad * 4;
            int gn  = n0 + no + j * 16 + l16;
            int nn  = gn & 1023;
            float bb = bp[(mode == 0) ? gn : nn];
#pragma unroll
            for (int r = 0; r < 4; ++r) {
                int gm = gmb + r;
                float v = acc[i][j][r] + bb;
                if (mode == 0) {
                    of32[(size_t)gm * 1024 + gn] = v;
                } else {
                    int b = gm >> 11, s = gm & 2047, h = nn >> 6, d = nn & 63;
                    if (which == 0)
                        ((unsigned short*)oq)[(((size_t)(b * NH + h)) * SS + s) * DH + d] = f2bf(v * QSCALE);
                    else if (which == 1)
                        ((unsigned short*)ok)[(((size_t)(b * NH + h)) * SS + s) * DH + d] = f2bf(v);
                    else
                        ((unsigned short*)ov)[(((size_t)(b * NH + h)) * DH + d) * SS + s] = f2bf(v);
                }
            }
        }
}

// ----- flash v13 (verified 52.6-53.4us): swapped QK^T (32x32x16), penalty
//       staged through LDS as MFMA C-in, in-register softmax via cvt_pk +
//       v_permlane32_swap, XCD-aware work remap, single-barrier double-
//       buffered glds staging, setprio around MFMA clusters. -----
__global__ __launch_bounds__(256, 4) void flash_split(
        const __hip_bfloat16* __restrict__ Q,
        const __hip_bfloat16* __restrict__ K,
        const __hip_bfloat16* __restrict__ Vt,
        const float* __restrict__ pf,     // -PENL2*(1-mask), [B,S]
        __hip_bfloat16* __restrict__ Op0, __hip_bfloat16* __restrict__ Op1,
        float* __restrict__ lp0, float* __restrict__ lp1) {
    // hw linear id (x fastest), bijective XCD remap: w = (bid%8)*128 + bid/8
    int bidl = blockIdx.x + (blockIdx.y << 4) + (blockIdx.z << 9);   // grid (16,32,2)
    int w = (bidl & 7) * 128 + (bidl >> 3);
    int q0 = (w & 15) * 128;
    int bh = (w >> 4) & 31;
    int z  = w >> 9;
    int b = bh >> 4, h = bh & (NH - 1);
    __hip_bfloat16* Op = z ? Op1 : Op0;
    float*          lp = z ? lp1 : lp0;
    int tid = threadIdx.x;
    int wave = tid >> 6, lane = tid & 63;
    int l31 = lane & 31, hi = lane >> 5, l7 = lane & 7;

    // [64 rows][64 elems] bf16 = 8 KB each, double-buffered: 32 KB total
    __shared__ alignas(16) __hip_bfloat16 sK[2][64 * 64];
    __shared__ alignas(16) __hip_bfloat16 sV[2][64 * 64];
    __shared__ alignas(16) float sPF[2][64];   // staged penalty per 64-key tile

    // Q fragment (B operand): row q = l31 (+wave*32), k(d) = dstep*16 + 8*hi + j
    const __hip_bfloat16* Qrow = Q + ((size_t)bh * SS + q0 + wave * 32 + l31) * DH;
    bf16x8 aq[4];
#pragma unroll
    for (int d_ = 0; d_ < 4; ++d_)
        aq[d_] = *(const bf16x8*)(Qrow + d_ * 16 + 8 * hi);

    const __hip_bfloat16* Kb = K + (size_t)bh * SS * DH;
    const __hip_bfloat16* Vb = Vt + (size_t)bh * DH * SS;
    const float* pfp = pf + b * SS;

    f32x16 z16;
#pragma unroll
    for (int r = 0; r < 16; ++r) z16[r] = 0.f;
    f32x16 O[2];
    O[0] = z16; O[1] = z16;
    f32x4 ls = (f32x4){0.f, 0.f, 0.f, 0.f};

    // swizzled read offsets (bytes): chunk c2 = (c<<1)|hi, xor'd with row&7 (= l7)
    int xo[4];
#pragma unroll
    for (int c = 0; c < 4; ++c) xo[c] = ((((c << 1) | hi) ^ l7) << 4);

    // staging geometry: per wave, lane l covers row (l>>3), chunk (l&7) -> dest byte = lane*16
    int r8 = lane >> 3, c8 = lane & 7;
    int ck = c8 ^ r8;   // inverse-swizzled SOURCE chunk (row&7 == r8)

    const int kbeg = z * (SS / 2);
    const int NT = (SS / 2) / 64;

    auto STAGE = [&](int bb, int k0) {
#pragma unroll
        for (int cc = 0; cc < 2; ++cc) {
            int row = cc * 32 + wave * 8 + r8;
            glds16(Kb + (size_t)(k0 + row) * DH + ck * 8, &sK[bb][row * 64 + c8 * 8]);
            glds16(Vb + (size_t)row * SS + k0 + ck * 8,  &sV[bb][row * 64 + c8 * 8]);
        }
        if (wave == 0)                      // 64 lanes x 4B = full 256B pf slice
            glds4(pfp + k0 + lane, &sPF[bb][0]);
    };

    STAGE(0, kbeg);
    __syncthreads();
    int cur = 0;
    for (int t = 0; t < NT; ++t) {
        int k0 = kbeg + t * 64;
        if (t + 1 < NT) STAGE(cur ^ 1, k0 + 64);
#pragma unroll
        for (int tt = 0; tt < 2; ++tt) {   // two 32-key tiles
            // --- QK^T swapped: C[k][q], k = (r&3)+8*(r>>2)+4*hi, q = l31 ---
            const char* pK = (const char*)&sK[cur][(tt * 32 + l31) * 64];
            bf16x8 kf[4];
#pragma unroll
            for (int d_ = 0; d_ < 4; ++d_)
                kf[d_] = *(const bf16x8*)(pK + xo[d_]);
            // C-in = log2-domain penalty from LDS (broadcast reads, staged ahead)
            f32x16 st;
#pragma unroll
            for (int g = 0; g < 4; ++g) {
                f32x4 pv = *(const f32x4*)&sPF[cur][32 * tt + 8 * g + 4 * hi];
#pragma unroll
                for (int j = 0; j < 4; ++j) st[4 * g + j] = pv[j];
            }
            __builtin_amdgcn_s_setprio(1);
#pragma unroll
            for (int d_ = 0; d_ < 4; ++d_)
                st = __builtin_amdgcn_mfma_f32_32x32x16_bf16(kf[d_], aq[d_], st, 0, 0, 0);
            __builtin_amdgcn_s_setprio(0);

            // --- softmax numerator in-register: e = exp2(s + pen) ---
#pragma unroll
            for (int g = 0; g < 4; ++g) {
#pragma unroll
                for (int j = 0; j < 4; ++j)
                    st[4 * g + j] = fexp2(st[4 * g + j]);
                ls[0] += st[4 * g];     ls[1] += st[4 * g + 1];
                ls[2] += st[4 * g + 2]; ls[3] += st[4 * g + 3];
            }

            // --- pack pairs to bf16: u[2g+p] holds keys 8g+4hi+2p+{0,1} ---
            unsigned int u[8];
#pragma unroll
            for (int g = 0; g < 4; ++g) {
                u[2 * g]     = pk2bf(st[4 * g],     st[4 * g + 1]);
                u[2 * g + 1] = pk2bf(st[4 * g + 2], st[4 * g + 3]);
            }

            // --- build PV A-frags (k = 16*ks + 8*hi + j) via permlane32_swap ---
#pragma unroll
            for (int kk = 0; kk < 2; ++kk) {   // ks = 2*tt + kk
                unsigned int w0 = u[4 * kk],     w2 = u[4 * kk + 2];
                unsigned int w1 = u[4 * kk + 1], w3 = u[4 * kk + 3];
                asm("v_permlane32_swap_b32 %0, %1" : "+v"(w0), "+v"(w2));
                asm("v_permlane32_swap_b32 %0, %1" : "+v"(w1), "+v"(w3));
                u32x4 paw; paw.x = w0; paw.y = w1; paw.z = w2; paw.w = w3;
                bf16x8 pa = __builtin_bit_cast(bf16x8, paw);
                int ks = 2 * tt + kk;
                __builtin_amdgcn_s_setprio(1);
#pragma unroll
                for (int dt_ = 0; dt_ < 2; ++dt_) {
                    const char* pV = (const char*)&sV[cur][(dt_ * 32 + l31) * 64];
                    bf16x8 vf = *(const bf16x8*)(pV + xo[ks]);
                    O[dt_] = __builtin_amdgcn_mfma_f32_32x32x16_bf16(pa, vf, O[dt_], 0, 0, 0);
                }
                __builtin_amdgcn_s_setprio(0);
            }
        }
        __syncthreads();
        cur ^= 1;
    }

    // --- epilogue: O is C[q][d], q = (r&3)+8*(r>>2)+4*hi, d = dt*32 + l31 ---
    unsigned short* op = (unsigned short*)Op;
    int qb = q0 + wave * 32;
#pragma unroll
    for (int dt_ = 0; dt_ < 2; ++dt_)
#pragma unroll
        for (int r = 0; r < 16; ++r) {
            int qq = (r & 3) + 8 * (r >> 2) + 4 * hi;
            op[((size_t)b * SS + qb + qq) * (NH * DH) + h * DH + dt_ * 32 + l31] =
                f2bf(O[dt_][r]);
        }
    float lt = ls[0] + ls[1] + ls[2] + ls[3];
    lt += __shfl_xor(lt, 32, 64);
    if (hi == 0)
        lp[(size_t)bh * SS + qb + l31] = lt;
}

// -------- combine: ctx = (O1+O2)/(l1+l2), bf16 --------
__global__ __launch_bounds__(256) void combine(
        const __hip_bfloat16* __restrict__ O1, const __hip_bfloat16* __restrict__ O2,
        const float* __restrict__ l1, const float* __restrict__ l2,
        __hip_bfloat16* __restrict__ ctx) {
    int i = blockIdx.x * 256 + threadIdx.x;
    size_t base = (size_t)i * 8;
    int row = i >> 7;
    int h   = (i >> 3) & 15;
    int b = row >> 11, s = row & 2047;
    size_t bhq = ((size_t)(b * NH + h)) * SS + s;
    float linv = 1.0f / (l1[bhq] + l2[bhq]);
    bf16x8 a = *(const bf16x8*)(O1 + base);
    bf16x8 c = *(const bf16x8*)(O2 + base);
    ushort4 o0, o1;
    o0.x = f2bf(((float)a[0] + (float)c[0]) * linv);
    o0.y = f2bf(((float)a[1] + (float)c[1]) * linv);
    o0.z = f2bf(((float)a[2] + (float)c[2]) * linv);
    o0.w = f2bf(((float)a[3] + (float)c[3]) * linv);
    o1.x = f2bf(((float)a[4] + (float)c[4]) * linv);
    o1.y = f2bf(((float)a[5] + (float)c[5]) * linv);
    o1.z = f2bf(((float)a[6] + (float)c[6]) * linv);
    o1.w = f2bf(((float)a[7] + (float)c[7]) * linv);
    ((ushort4*)(ctx + base))[0] = o0;
    ((ushort4*)(ctx + base + 4))[0] = o1;
}

extern "C" void kernel_launch(void* const* d_in, const int* in_sizes, int n_in,
                              void* d_out, int out_size, void* d_ws, size_t ws_size,
                              hipStream_t stream) {
    const float* X    = (const float*)d_in[0];
    const float* mask = (const float*)d_in[1];
    const float* Wq   = (const float*)d_in[2];
    const float* bq   = (const float*)d_in[3];
    const float* Wk   = (const float*)d_in[4];
    const float* bk   = (const float*)d_in[5];
    const float* Wv   = (const float*)d_in[6];
    const float* bv   = (const float*)d_in[7];
    const float* Wo   = (const float*)d_in[8];
    const float* bo   = (const float*)d_in[9];
    float* out = (float*)d_out;

    const size_t MB = 1u << 20;
    char* ws = (char*)d_ws;
    __hip_bfloat16* Xbf = (__hip_bfloat16*)(ws);             // 0-8   (later ctx)
    __hip_bfloat16* Op0 = (__hip_bfloat16*)(ws + 8 * MB);    // 8-16
    __hip_bfloat16* Wt4 = (__hip_bfloat16*)(ws + 16 * MB);   // 16-24 (Wq,Wk,Wv,Wo ^T)
    float*          lp0 = (float*)(ws + 24 * MB);            // 24-24.25
    float*          lp1 = (float*)(ws + 25 * MB);            // 25-25.25
    float*          pf  = (float*)(ws + 26 * MB);            // 26-26.02 (penalty)
    __hip_bfloat16* Qw  = (__hip_bfloat16*)(ws + 32 * MB);   // 32-40
    __hip_bfloat16* Kw  = (__hip_bfloat16*)(ws + 40 * MB);   // 40-48
    __hip_bfloat16* Vt  = (__hip_bfloat16*)(ws + 48 * MB);   // 48-56
    __hip_bfloat16* Op1 = (__hip_bfloat16*)(ws + 56 * MB);   // 56-64
    __hip_bfloat16* Wot = Wt4 + (size_t)3 * DIM * DIM;       // 22-24

    dim3 pgrd(32, 32, 5);
    prep<<<pgrd, 256, 0, stream>>>(X, Wq, Wk, Wv, Wo, mask, pf, Wt4, (ushort4*)Xbf);

    dim3 qkvgrd(3 * DIM / 128, (BB * SS) / BM);  // (24, 32) = 768 blocks, %8==0
    gemm_bf<128><<<qkvgrd, 512, 0, stream>>>(Xbf, Wt4, bq, bk, bv,
                                             Qw, Kw, Vt, nullptr, 1);

    dim3 agrd(SS / 128, BB * NH, 2);             // (16, 32, 2) = 1024 blocks
    flash_split<<<agrd, 256, 0, stream>>>(Qw, Kw, Vt, pf, Op0, Op1, lp0, lp1);

    // ctx overwrites Xbf (dead after QKV GEMM)
    combine<<<dim3(2048), 256, 0, stream>>>(Op0, Op1, lp0, lp1, Xbf);

    dim3 ogrd(DIM / 64, (BB * SS) / BM);         // (16, 32) = 512 blocks, %8==0
    gemm_bf<64><<<ogrd, 512, 0, stream>>>(Xbf, Wot, bo, nullptr, nullptr,
                                          nullptr, nullptr, nullptr, out, 0);
}